// Round 4
// baseline (550.064 us; speedup 1.0000x reference)
//
#include <hip/hip_runtime.h>
#include <hip/hip_fp16.h>
#include <stdint.h>

typedef _Float16 f16;
typedef _Float16 f16x8 __attribute__((ext_vector_type(8)));
typedef _Float16 f16x4 __attribute__((ext_vector_type(4)));
typedef _Float16 f16x2 __attribute__((ext_vector_type(2)));
typedef float f32x4 __attribute__((ext_vector_type(4)));
typedef float f32x2 __attribute__((ext_vector_type(2)));

#define B_ 4
#define N_ 16384
#define M_ 4096
#define C1_ 128
#define C2_ 256
#define BNTOT 65536  // B_*N_

#define SPLIT 16
#define CHUNK (M_ / SPLIT)  // 256

// ---------------- async global->LDS 16B ----------------
__device__ __forceinline__ void gload_lds16(const void* g, void* l) {
    __builtin_amdgcn_global_load_lds(
        (const __attribute__((address_space(1))) void*)g,
        (__attribute__((address_space(3))) void*)l, 16, 0, 0);
}

// ---------------- kernel: fp32 -> fp16 convert (all 3 weight mats) ----------------
__global__ void conv_f16_kernel(const float* __restrict__ s0, f16* __restrict__ d0,
                                const float* __restrict__ s1, f16* __restrict__ d1,
                                const float* __restrict__ s2, f16* __restrict__ d2) {
    int i = blockIdx.x * blockDim.x + threadIdx.x;
    if (i < 98304) d0[i] = (f16)s0[i];
    if (i < 65536) d1[i] = (f16)s1[i];
    if (i < 32768) d2[i] = (f16)s2[i];
}

// ---------------- kernel: 3-NN partial search over one M-chunk ----------------
// grid = (BNTOT/256) * SPLIT blocks. Each block: 256 query points x one
// 256-candidate chunk of xyz2 (staged SoA in 3KB LDS).
// Direct squared-diff distance (no cancellation). Branchless sorted-insert:
// c0 => c1 => c2 (sorted invariant), strict < keeps lowest index on ties
// exactly like a sequential scan / lax.top_k.
__global__ __launch_bounds__(256) void nn_part_kernel(
    const float* __restrict__ xyz1, const float* __restrict__ xyz2,
    f32x2* __restrict__ cdi) {
    __shared__ __align__(16) float xs[CHUNK];
    __shared__ __align__(16) float ys[CHUNK];
    __shared__ __align__(16) float zs[CHUNK];
    int bid = blockIdx.x;
    int part = bid & (SPLIT - 1);
    int pblk = bid >> 4;                 // 0..255 point-block
    int b = pblk >> 6;                   // 64 point-blocks per batch
    int m0 = part * CHUNK;
    const float* x2 = xyz2 + ((size_t)b * M_ + m0) * 3;
    {
        int m = threadIdx.x;  // CHUNK == blockDim.x
        xs[m] = x2[m * 3 + 0];
        ys[m] = x2[m * 3 + 1];
        zs[m] = x2[m * 3 + 2];
    }
    __syncthreads();
    size_t p = (size_t)pblk * 256 + threadIdx.x;
    const float* q = xyz1 + p * 3;
    float qx = q[0], qy = q[1], qz = q[2];
    float k0 = 3.4e38f, k1 = 3.4e38f, k2 = 3.4e38f;
    int i0 = 0, i1 = 0, i2 = 0;
    for (int m = 0; m < CHUNK; m += 4) {
        f32x4 xv = *(const f32x4*)&xs[m];   // uniform addr -> LDS broadcast
        f32x4 yv = *(const f32x4*)&ys[m];
        f32x4 zv = *(const f32x4*)&zs[m];
#pragma unroll
        for (int u = 0; u < 4; ++u) {
            float dx = qx - xv[u], dy = qy - yv[u], dz = qz - zv[u];
            float x = fmaf(dx, dx, fmaf(dy, dy, dz * dz));
            int ix = m0 + m + u;
            bool c0 = x < k0, c1 = x < k1, c2 = x < k2;
            float mx = c0 ? k0 : x;  int mxi = c0 ? i0 : ix;   // displaced from rank0
            float m2 = c1 ? k1 : x;  int m2i = c1 ? i1 : ix;   // displaced from rank1
            k0 = c0 ? x : k0;   i0 = c0 ? ix : i0;
            k1 = c1 ? mx : k1;  i1 = c1 ? mxi : i1;
            k2 = c2 ? m2 : k2;  i2 = c2 ? m2i : i2;
        }
    }
    f32x2 e0 = {k0, __int_as_float(i0)};
    f32x2 e1 = {k1, __int_as_float(i1)};
    f32x2 e2 = {k2, __int_as_float(i2)};
    f32x2* out = cdi + (p * SPLIT + part) * 3;
    __builtin_nontemporal_store(e0, out + 0);
    __builtin_nontemporal_store(e1, out + 1);
    __builtin_nontemporal_store(e2, out + 2);
}

// ---------------- kernel: merge SPLIT x 3 candidates -> top-3 + weights ----------------
// Chunks visited in ascending index order, strict < insertion -> identical
// tie-break to a single sequential scan (= lax.top_k lowest-index-first).
__global__ __launch_bounds__(256) void nn_merge_kernel(
    const f32x2* __restrict__ cdi,
    int* __restrict__ idx_out, float* __restrict__ w_out) {
    size_t p = (size_t)blockIdx.x * 256 + threadIdx.x;
    const f32x2* cp = cdi + p * (SPLIT * 3);
    float k0 = 3.4e38f, k1 = 3.4e38f, k2 = 3.4e38f;
    int i0 = 0, i1 = 0, i2 = 0;
#pragma unroll
    for (int t = 0; t < SPLIT * 3; ++t) {
        f32x2 e = cp[t];
        float x = e[0];
        int ix = __float_as_int(e[1]);
        bool c0 = x < k0, c1 = x < k1, c2 = x < k2;
        float mx = c0 ? k0 : x;  int mxi = c0 ? i0 : ix;
        float m2 = c1 ? k1 : x;  int m2i = c1 ? i1 : ix;
        k0 = c0 ? x : k0;   i0 = c0 ? ix : i0;
        k1 = c1 ? mx : k1;  i1 = c1 ? mxi : i1;
        k2 = c2 ? m2 : k2;  i2 = c2 ? m2i : i2;
    }
    float w0 = 1.0f / (k0 + 1e-8f);
    float w1 = 1.0f / (k1 + 1e-8f);
    float w2 = 1.0f / (k2 + 1e-8f);
    float ws = w0 + w1 + w2;
    w0 /= ws; w1 /= ws; w2 /= ws;
    idx_out[p * 3 + 0] = i0; idx_out[p * 3 + 1] = i1; idx_out[p * 3 + 2] = i2;
    w_out[p * 3 + 0] = w0;  w_out[p * 3 + 1] = w1;  w_out[p * 3 + 2] = w2;
}

// ---------------- kernel: gather-interp + concat -> x0 (fp16) ----------------
// One wave per point. XCD-confinement swizzle: batch = (blk&7)>>1, so each
// XCD's private L2 only caches ONE batch's 4MB slice of pts2 -> gathers hit L2.
// pts1 / x0 use nontemporal (streamed once) to avoid evicting pts2 from L2.
__global__ __launch_bounds__(256) void interp_kernel(
    const float* __restrict__ pts1, const float* __restrict__ pts2,
    const int* __restrict__ idxb, const float* __restrict__ wb,
    f16* __restrict__ x0) {
    int wave = threadIdx.x >> 6, lane = threadIdx.x & 63;
    int blk = blockIdx.x;                  // 16384 blocks, 4 points each
    int xcd = blk & 7;
    int batch = xcd >> 1;
    int pib = ((blk >> 3) << 1) + (xcd & 1);  // 0..4095 point-block within batch
    size_t p = ((size_t)batch << 14) + (size_t)pib * 4 + wave;
    int j0 = idxb[p * 3 + 0], j1 = idxb[p * 3 + 1], j2 = idxb[p * 3 + 2];
    float w0 = wb[p * 3 + 0], w1 = wb[p * 3 + 1], w2 = wb[p * 3 + 2];
    const float* base2 = pts2 + (size_t)batch * M_ * C2_;
    f32x4 a = *(const f32x4*)(base2 + (size_t)j0 * C2_ + lane * 4);
    f32x4 bv = *(const f32x4*)(base2 + (size_t)j1 * C2_ + lane * 4);
    f32x4 c = *(const f32x4*)(base2 + (size_t)j2 * C2_ + lane * 4);
    f16* xrow = x0 + p * (C1_ + C2_);
    f16x4 o;
#pragma unroll
    for (int j = 0; j < 4; ++j)
        o[j] = (f16)(w0 * a[j] + w1 * bv[j] + w2 * c[j]);
    __builtin_nontemporal_store(o, (f16x4*)(xrow + C1_ + lane * 4));
    f32x2 p1 = __builtin_nontemporal_load((const f32x2*)(pts1 + p * C1_ + lane * 2));
    f16x2 o2; o2[0] = (f16)p1[0]; o2[1] = (f16)p1[1];
    __builtin_nontemporal_store(o2, (f16x2*)(xrow + lane * 2));
}

// ---------------- kernel: fp16 GEMM, H[m][o] = sum_c A[m][c] * W[o][c] ----------------
// 128x128 tile, BK=64, 4 waves (2x2), global_load_lds staging (m97 structure).
template <int K>
__global__ __launch_bounds__(256) void gemm_f16(
    const f16* __restrict__ A, const f16* __restrict__ W,
    f16* __restrict__ H, int Nn) {
    __shared__ __align__(16) f16 As[128 * 64];
    __shared__ __align__(16) f16 Bs[128 * 64];
    int tid = threadIdx.x;
    int lane = tid & 63, wave = tid >> 6;
    int wr = wave >> 1, wc = wave & 1;
    int bm0 = blockIdx.x * 128, bn0 = blockIdx.y * 128;
    const f16* Ab = A + (size_t)bm0 * K;
    const f16* Wb = W + (size_t)bn0 * K;
    int r = tid >> 3;            // 0..31
    int cc = (tid & 7) * 8;      // 0..56, 8 f16 = 16B
    f32x4 acc[4][4] = {};
    for (int kt = 0; kt < K; kt += 64) {
        __syncthreads();
#pragma unroll
        for (int i = 0; i < 4; ++i) {
            gload_lds16(Ab + (size_t)(i * 32 + r) * K + kt + cc, &As[(i * 32 + r) * 64 + cc]);
            gload_lds16(Wb + (size_t)(i * 32 + r) * K + kt + cc, &Bs[(i * 32 + r) * 64 + cc]);
        }
        __syncthreads();
#pragma unroll
        for (int kk = 0; kk < 2; ++kk) {
            f16x8 af[4], bf[4];
            int koff = kk * 32 + (lane >> 4) * 8;
#pragma unroll
            for (int mt = 0; mt < 4; ++mt)
                af[mt] = *(const f16x8*)&As[(wr * 64 + mt * 16 + (lane & 15)) * 64 + koff];
#pragma unroll
            for (int nt = 0; nt < 4; ++nt)
                bf[nt] = *(const f16x8*)&Bs[(wc * 64 + nt * 16 + (lane & 15)) * 64 + koff];
#pragma unroll
            for (int mt = 0; mt < 4; ++mt)
#pragma unroll
                for (int nt = 0; nt < 4; ++nt)
                    acc[mt][nt] = __builtin_amdgcn_mfma_f32_16x16x32_f16(af[mt], bf[nt], acc[mt][nt], 0, 0, 0);
        }
    }
    // epilogue: C/D layout col=lane&15, row=(lane>>4)*4+reg
    int rr = (lane >> 4) * 4;
    int cl = lane & 15;
#pragma unroll
    for (int mt = 0; mt < 4; ++mt) {
#pragma unroll
        for (int nt = 0; nt < 4; ++nt) {
            int row = bm0 + wr * 64 + mt * 16 + rr;
            int col = bn0 + wc * 64 + nt * 16 + cl;
#pragma unroll
            for (int j = 0; j < 4; ++j)
                H[(size_t)(row + j) * Nn + col] = (f16)acc[mt][nt][j];
        }
    }
}

// ---------------- kernel: per-channel sum/sumsq (atomics) ----------------
__global__ __launch_bounds__(256) void stats_kernel(
    const f16* __restrict__ H, float* __restrict__ sums, float* __restrict__ sumsq, int Nn) {
    int tid = threadIdx.x;
    int c = tid & (Nn - 1);
    int rsub = tid / Nn;
    int rstep = 256 / Nn;
    int r0 = blockIdx.x * 256;
    float s = 0.f, s2 = 0.f;
    for (int rr = r0 + rsub; rr < r0 + 256; rr += rstep) {
        float v = (float)H[(size_t)rr * Nn + c];
        s += v;
        s2 = fmaf(v, v, s2);
    }
    atomicAdd(&sums[c], s);
    atomicAdd(&sumsq[c], s2);
}

// ---------------- kernel: finalize BN -> scale/shift ----------------
__global__ void finalize_kernel(const float* __restrict__ sums, const float* __restrict__ sumsq,
                                const float* __restrict__ g, const float* __restrict__ be,
                                float* __restrict__ scale, float* __restrict__ shift, int Nn) {
    int c = threadIdx.x;
    if (c < Nn) {
        const float invM = 1.0f / 65536.0f;
        float mean = sums[c] * invM;
        float var = sumsq[c] * invM - mean * mean;
        float rstd = rsqrtf(var + 1e-5f);
        float sc = rstd * g[c];
        scale[c] = sc;
        shift[c] = be[c] - mean * sc;
    }
}

// ---------------- kernel: BN-apply + ReLU (in-place f16 or fp32 out) ----------------
template <bool OUT16>
__global__ __launch_bounds__(256) void bnrelu_kernel(
    const f16* __restrict__ H, const float* __restrict__ scale, const float* __restrict__ shift,
    f16* __restrict__ o16, float* __restrict__ o32, int Nn) {
    size_t t = (size_t)blockIdx.x * 256 + threadIdx.x;
    size_t base = t * 8;
    int c0 = (int)(base & (size_t)(Nn - 1));
    f16x8 v = *(const f16x8*)(H + base);
    float r[8];
#pragma unroll
    for (int j = 0; j < 8; ++j)
        r[j] = fmaxf(0.0f, fmaf((float)v[j], scale[c0 + j], shift[c0 + j]));
    if (OUT16) {
        f16x8 ov;
#pragma unroll
        for (int j = 0; j < 8; ++j) ov[j] = (f16)r[j];
        *(f16x8*)(o16 + base) = ov;
    } else {
        f32x4 a = {r[0], r[1], r[2], r[3]};
        f32x4 b = {r[4], r[5], r[6], r[7]};
        __builtin_nontemporal_store(a, (f32x4*)(o32 + base));
        __builtin_nontemporal_store(b, (f32x4*)(o32 + base + 4));
    }
}

extern "C" void kernel_launch(void* const* d_in, const int* in_sizes, int n_in,
                              void* d_out, int out_size, void* d_ws, size_t ws_size,
                              hipStream_t stream) {
    const float* xyz1 = (const float*)d_in[0];
    const float* xyz2 = (const float*)d_in[1];
    const float* pts1 = (const float*)d_in[2];
    const float* pts2 = (const float*)d_in[3];
    const float* w0f = (const float*)d_in[4];
    const float* g0 = (const float*)d_in[6];
    const float* be0 = (const float*)d_in[7];
    const float* w1f = (const float*)d_in[8];
    const float* g1 = (const float*)d_in[10];
    const float* be1 = (const float*)d_in[11];
    const float* w2f = (const float*)d_in[12];
    const float* g2 = (const float*)d_in[14];
    const float* be2 = (const float*)d_in[15];
    // biases b{li} cancel exactly under training-mode BN -> unused.

    char* ws = (char*)d_ws;
    // layout (bytes):
    //   x0  : [0, 50331648)              65536x384 f16; reused as bufB after layer0
    //   bufA: [50331648, +33554432)      65536x256 f16
    //         (candidate pair buffer cdi aliases bufA: dead before layer-0 GEMM;
    //          65536*16*3*8B = 25.2MB < 33.5MB)
    //   wb  : [83886080, +393216)        all three weight matrices, f16
    //   idx : [84279296, +786432)        65536x3 i32
    //   wgt : [85065728, +786432)        65536x3 f32
    //   stat: [85852160, +4096)          sums/sumsq/scale/shift x256 f32
    f16* x0 = (f16*)(ws + 0);
    f16* bufA = (f16*)(ws + 50331648);
    f16* bufB = x0;  // alias: x0 dead after layer-0 GEMM
    f32x2* cdi = (f32x2*)(ws + 50331648);
    f16* wb0 = (f16*)(ws + 83886080);
    f16* wb1 = wb0 + 98304;
    f16* wb2 = wb1 + 65536;
    int* idxb = (int*)(ws + 84279296);
    float* wgt = (float*)(ws + 85065728);
    float* stats = (float*)(ws + 85852160);
    float* sums = stats, *sumsq = stats + 256, *scale = stats + 512, *shift = stats + 768;

    // weights -> fp16 (single kernel)
    conv_f16_kernel<<<384, 256, 0, stream>>>(w0f, wb0, w1f, wb1, w2f, wb2);

    // 3-NN (split-M partial scan + merge) + interpolation + concat
    nn_part_kernel<<<(BNTOT / 256) * SPLIT, 256, 0, stream>>>(xyz1, xyz2, cdi);
    nn_merge_kernel<<<BNTOT / 256, 256, 0, stream>>>(cdi, idxb, wgt);
    interp_kernel<<<BNTOT / 4, 256, 0, stream>>>(pts1, pts2, idxb, wgt, x0);

    // ---- layer 0: 384 -> 256 ----
    gemm_f16<384><<<dim3(512, 2), 256, 0, stream>>>(x0, wb0, bufA, 256);
    hipMemsetAsync(sums, 0, 2048, stream);
    stats_kernel<<<256, 256, 0, stream>>>(bufA, sums, sumsq, 256);
    finalize_kernel<<<1, 256, 0, stream>>>(sums, sumsq, g0, be0, scale, shift, 256);
    bnrelu_kernel<true><<<8192, 256, 0, stream>>>(bufA, scale, shift, bufA, nullptr, 256);

    // ---- layer 1: 256 -> 256 ----
    gemm_f16<256><<<dim3(512, 2), 256, 0, stream>>>(bufA, wb1, bufB, 256);
    hipMemsetAsync(sums, 0, 2048, stream);
    stats_kernel<<<256, 256, 0, stream>>>(bufB, sums, sumsq, 256);
    finalize_kernel<<<1, 256, 0, stream>>>(sums, sumsq, g1, be1, scale, shift, 256);
    bnrelu_kernel<true><<<8192, 256, 0, stream>>>(bufB, scale, shift, bufB, nullptr, 256);

    // ---- layer 2: 256 -> 128 ----
    gemm_f16<256><<<dim3(512, 1), 256, 0, stream>>>(bufB, wb2, bufA, 128);
    hipMemsetAsync(sums, 0, 2048, stream);
    stats_kernel<<<256, 256, 0, stream>>>(bufA, sums, sumsq, 128);
    finalize_kernel<<<1, 256, 0, stream>>>(sums, sumsq, g2, be2, scale, shift, 128);
    bnrelu_kernel<false><<<4096, 256, 0, stream>>>(bufA, scale, shift, nullptr, (float*)d_out, 128);
}

// Round 8
// 419.448 us; speedup vs baseline: 1.3114x; 1.3114x over previous
//
#include <hip/hip_runtime.h>
#include <hip/hip_fp16.h>
#include <stdint.h>

typedef _Float16 f16;
typedef _Float16 f16x8 __attribute__((ext_vector_type(8)));
typedef _Float16 f16x4 __attribute__((ext_vector_type(4)));
typedef _Float16 f16x2 __attribute__((ext_vector_type(2)));
typedef float f32x4 __attribute__((ext_vector_type(4)));
typedef float f32x2 __attribute__((ext_vector_type(2)));

#define B_ 4
#define N_ 16384
#define M_ 4096
#define C1_ 128
#define C2_ 256
#define BNTOT 65536  // B_*N_

#define SPLIT 16
#define CHUNK (M_ / SPLIT)  // 256

// ---------------- async global->LDS 16B ----------------
__device__ __forceinline__ void gload_lds16(const void* g, void* l) {
    __builtin_amdgcn_global_load_lds(
        (const __attribute__((address_space(1))) void*)g,
        (__attribute__((address_space(3))) void*)l, 16, 0, 0);
}

// ---------------- kernel: fp32 -> fp16 weights + zero stats buffers ----------------
__global__ void conv_f16_kernel(const float* __restrict__ s0, f16* __restrict__ d0,
                                const float* __restrict__ s1, f16* __restrict__ d1,
                                const float* __restrict__ s2, f16* __restrict__ d2,
                                float* __restrict__ statz) {
    int i = blockIdx.x * blockDim.x + threadIdx.x;
    if (i < 98304) d0[i] = (f16)s0[i];
    if (i < 65536) d1[i] = (f16)s1[i];
    if (i < 32768) d2[i] = (f16)s2[i];
    if (i < 1536) statz[i] = 0.0f;   // 3 layers x (sums[256], sumsq[256])
}

// ---------------- kernel: 3-NN partial search over one M-chunk ----------------
// EXACT fp32 d2 compares (packed-key truncation proved fatal in R5: 20-bit
// d2 quantum ~4e-6 vs gap density 1/0.005 -> ~50 wrong neighbors).
// Branchy sorted insert (proven in R2): wave-any branch, rare after warmup.
// Direct squared-diff (no cancellation); strict < == lax.top_k tie-break.
__global__ __launch_bounds__(256) void nn_part_kernel(
    const float* __restrict__ xyz1, const float* __restrict__ xyz2,
    f32x2* __restrict__ ck) {
    __shared__ __align__(16) float xs[CHUNK];
    __shared__ __align__(16) float ys[CHUNK];
    __shared__ __align__(16) float zs[CHUNK];
    int bid = blockIdx.x;                // grid = (BNTOT/256) * SPLIT = 4096
    int part = bid & (SPLIT - 1);
    int pblk = bid >> 4;                 // 0..255 point-block
    int b = pblk >> 6;                   // 64 point-blocks per batch
    int m0 = part * CHUNK;
    const float* x2 = xyz2 + ((size_t)b * M_ + m0) * 3;
    {
        int m = threadIdx.x;  // CHUNK == blockDim.x
        xs[m] = x2[m * 3 + 0];
        ys[m] = x2[m * 3 + 1];
        zs[m] = x2[m * 3 + 2];
    }
    __syncthreads();
    size_t p = (size_t)pblk * 256 + threadIdx.x;
    const float* q = xyz1 + p * 3;
    float qx = q[0], qy = q[1], qz = q[2];
    float k0 = 3.4e38f, k1 = 3.4e38f, k2 = 3.4e38f;
    int i0 = 0, i1 = 0, i2 = 0;
    for (int m = 0; m < CHUNK; m += 4) {
        f32x4 xv = *(const f32x4*)&xs[m];   // uniform addr -> LDS broadcast
        f32x4 yv = *(const f32x4*)&ys[m];
        f32x4 zv = *(const f32x4*)&zs[m];
#pragma unroll
        for (int u = 0; u < 4; ++u) {
            float dx = qx - xv[u], dy = qy - yv[u], dz = qz - zv[u];
            float d2 = fmaf(dx, dx, fmaf(dy, dy, dz * dz));
            int mi = m0 + m + u;
            if (d2 < k2) {                   // rare after warmup
                if (d2 < k1) {
                    k2 = k1; i2 = i1;
                    if (d2 < k0) { k1 = k0; i1 = i0; k0 = d2; i0 = mi; }
                    else         { k1 = d2; i1 = mi; }
                } else { k2 = d2; i2 = mi; }
            }
        }
    }
    // rank-major [rank][part][point] -> each store fully coalesced (8B/lane)
    f32x2 e0 = {k0, __int_as_float(i0)};
    f32x2 e1 = {k1, __int_as_float(i1)};
    f32x2 e2 = {k2, __int_as_float(i2)};
    __builtin_nontemporal_store(e0, ck + (size_t)(0 * SPLIT + part) * BNTOT + p);
    __builtin_nontemporal_store(e1, ck + (size_t)(1 * SPLIT + part) * BNTOT + p);
    __builtin_nontemporal_store(e2, ck + (size_t)(2 * SPLIT + part) * BNTOT + p);
}

// ---------------- kernel: merge SPLIT x 3 candidates -> top-3 + weights ----------------
// Parts ascending, ranks ascending within part, strict < insertion ->
// identical result/tie-break to one sequential ascending-index scan.
__global__ __launch_bounds__(256) void nn_merge_kernel(
    const f32x2* __restrict__ ck,
    int* __restrict__ idx_out, float* __restrict__ w_out) {
    size_t p = (size_t)blockIdx.x * 256 + threadIdx.x;
    float k0 = 3.4e38f, k1 = 3.4e38f, k2 = 3.4e38f;
    int i0 = 0, i1 = 0, i2 = 0;
#pragma unroll
    for (int part = 0; part < SPLIT; ++part) {
#pragma unroll
        for (int rank = 0; rank < 3; ++rank) {
            f32x2 e = __builtin_nontemporal_load(ck + (size_t)(rank * SPLIT + part) * BNTOT + p);
            float x = e[0];
            int ix = __float_as_int(e[1]);
            bool c0 = x < k0, c1 = x < k1, c2 = x < k2;
            float mx = c0 ? k0 : x;  int mxi = c0 ? i0 : ix;
            float m2 = c1 ? k1 : x;  int m2i = c1 ? i1 : ix;
            k0 = c0 ? x : k0;   i0 = c0 ? ix : i0;
            k1 = c1 ? mx : k1;  i1 = c1 ? mxi : i1;
            k2 = c2 ? m2 : k2;  i2 = c2 ? m2i : i2;
        }
    }
    float w0 = 1.0f / (k0 + 1e-8f);
    float w1 = 1.0f / (k1 + 1e-8f);
    float w2 = 1.0f / (k2 + 1e-8f);
    float ws = w0 + w1 + w2;
    w0 /= ws; w1 /= ws; w2 /= ws;
    idx_out[p * 3 + 0] = i0; idx_out[p * 3 + 1] = i1; idx_out[p * 3 + 2] = i2;
    w_out[p * 3 + 0] = w0;  w_out[p * 3 + 1] = w1;  w_out[p * 3 + 2] = w2;
}

// ---------------- kernel: gather-interp + concat -> x0 (fp16) ----------------
// One wave per point. pts1 / x0 use nontemporal (streamed once) so the
// streaming traffic doesn't evict pts2 gather rows from L2.
__global__ __launch_bounds__(256) void interp_kernel(
    const float* __restrict__ pts1, const float* __restrict__ pts2,
    const int* __restrict__ idxb, const float* __restrict__ wb,
    f16* __restrict__ x0) {
    int wave = threadIdx.x >> 6, lane = threadIdx.x & 63;
    size_t p = (size_t)blockIdx.x * 4 + wave;
    int batch = (int)(p >> 14);  // N_=16384
    int j0 = idxb[p * 3 + 0], j1 = idxb[p * 3 + 1], j2 = idxb[p * 3 + 2];
    float w0 = wb[p * 3 + 0], w1 = wb[p * 3 + 1], w2 = wb[p * 3 + 2];
    const float* base2 = pts2 + (size_t)batch * M_ * C2_;
    f32x4 a = *(const f32x4*)(base2 + (size_t)j0 * C2_ + lane * 4);
    f32x4 bv = *(const f32x4*)(base2 + (size_t)j1 * C2_ + lane * 4);
    f32x4 c = *(const f32x4*)(base2 + (size_t)j2 * C2_ + lane * 4);
    f16* xrow = x0 + p * (C1_ + C2_);
    f16x4 o;
#pragma unroll
    for (int j = 0; j < 4; ++j)
        o[j] = (f16)(w0 * a[j] + w1 * bv[j] + w2 * c[j]);
    __builtin_nontemporal_store(o, (f16x4*)(xrow + C1_ + lane * 4));
    f32x2 p1 = __builtin_nontemporal_load((const f32x2*)(pts1 + p * C1_ + lane * 2));
    f16x2 o2; o2[0] = (f16)p1[0]; o2[1] = (f16)p1[1];
    __builtin_nontemporal_store(o2, (f16x2*)(xrow + lane * 2));
}

// ---------------- kernel: fp16 GEMM + fused BN-stats epilogue ----------------
// H[m][o] = sum_c A[m][c] * W[o][c]. 128x128 tile, BK=64, 4 waves (2x2),
// global_load_lds staging. Epilogue also accumulates per-channel sum/sumsq
// (on fp32 acc, pre-f16-rounding) via shfl_xor reduce + atomics -> deletes
// the separate stats pass (3 dispatches + 96MB of re-reads).
template <int K>
__global__ __launch_bounds__(256) void gemm_f16(
    const f16* __restrict__ A, const f16* __restrict__ W,
    f16* __restrict__ H, float* __restrict__ sums, float* __restrict__ sumsq,
    int Nn) {
    __shared__ __align__(16) f16 As[128 * 64];
    __shared__ __align__(16) f16 Bs[128 * 64];
    int tid = threadIdx.x;
    int lane = tid & 63, wave = tid >> 6;
    int wr = wave >> 1, wc = wave & 1;
    int bm0 = blockIdx.x * 128, bn0 = blockIdx.y * 128;
    const f16* Ab = A + (size_t)bm0 * K;
    const f16* Wb = W + (size_t)bn0 * K;
    int r = tid >> 3;            // 0..31
    int cc = (tid & 7) * 8;      // 0..56, 8 f16 = 16B
    f32x4 acc[4][4] = {};
    for (int kt = 0; kt < K; kt += 64) {
        __syncthreads();
#pragma unroll
        for (int i = 0; i < 4; ++i) {
            gload_lds16(Ab + (size_t)(i * 32 + r) * K + kt + cc, &As[(i * 32 + r) * 64 + cc]);
            gload_lds16(Wb + (size_t)(i * 32 + r) * K + kt + cc, &Bs[(i * 32 + r) * 64 + cc]);
        }
        __syncthreads();
#pragma unroll
        for (int kk = 0; kk < 2; ++kk) {
            f16x8 af[4], bf[4];
            int koff = kk * 32 + (lane >> 4) * 8;
#pragma unroll
            for (int mt = 0; mt < 4; ++mt)
                af[mt] = *(const f16x8*)&As[(wr * 64 + mt * 16 + (lane & 15)) * 64 + koff];
#pragma unroll
            for (int nt = 0; nt < 4; ++nt)
                bf[nt] = *(const f16x8*)&Bs[(wc * 64 + nt * 16 + (lane & 15)) * 64 + koff];
#pragma unroll
            for (int mt = 0; mt < 4; ++mt)
#pragma unroll
                for (int nt = 0; nt < 4; ++nt)
                    acc[mt][nt] = __builtin_amdgcn_mfma_f32_16x16x32_f16(af[mt], bf[nt], acc[mt][nt], 0, 0, 0);
        }
    }
    // epilogue: C/D layout col=lane&15, row=(lane>>4)*4+reg
    int rr = (lane >> 4) * 4;
    int cl = lane & 15;
#pragma unroll
    for (int mt = 0; mt < 4; ++mt) {
#pragma unroll
        for (int nt = 0; nt < 4; ++nt) {
            int row = bm0 + wr * 64 + mt * 16 + rr;
            int col = bn0 + wc * 64 + nt * 16 + cl;
#pragma unroll
            for (int j = 0; j < 4; ++j)
                H[(size_t)(row + j) * Nn + col] = (f16)acc[mt][nt][j];
        }
    }
    // fused per-channel stats: this wave's 64 rows of 16 cols per nt.
    // 4 lane-groups (lane>>4) hold the same col -> butterfly combine.
#pragma unroll
    for (int nt = 0; nt < 4; ++nt) {
        float s = 0.f, s2 = 0.f;
#pragma unroll
        for (int mt = 0; mt < 4; ++mt)
#pragma unroll
            for (int j = 0; j < 4; ++j) {
                float v = acc[mt][nt][j];
                s += v;
                s2 = fmaf(v, v, s2);
            }
        s += __shfl_xor(s, 16);
        s2 += __shfl_xor(s2, 16);
        s += __shfl_xor(s, 32);
        s2 += __shfl_xor(s2, 32);
        if (lane < 16) {
            int c = bn0 + wc * 64 + nt * 16 + lane;
            atomicAdd(&sums[c], s);
            atomicAdd(&sumsq[c], s2);
        }
    }
}

// ---------------- kernel: BN finalize + apply + ReLU (fused) ----------------
// Each block recomputes scale/shift for its channels into LDS, then applies.
template <bool OUT16>
__global__ __launch_bounds__(256) void bnrelu_kernel(
    const f16* __restrict__ H, const float* __restrict__ sums, const float* __restrict__ sumsq,
    const float* __restrict__ g, const float* __restrict__ be,
    f16* __restrict__ o16, float* __restrict__ o32, int Nn) {
    __shared__ float ssc[256], ssh[256];
    int tid = threadIdx.x;
    if (tid < Nn) {
        const float invM = 1.0f / 65536.0f;
        float mean = sums[tid] * invM;
        float var = sumsq[tid] * invM - mean * mean;
        float rstd = rsqrtf(var + 1e-5f);
        float sc = rstd * g[tid];
        ssc[tid] = sc;
        ssh[tid] = be[tid] - mean * sc;
    }
    __syncthreads();
    size_t t = (size_t)blockIdx.x * 256 + tid;
    size_t base = t * 8;
    int c0 = (int)(base & (size_t)(Nn - 1));
    f16x8 v = *(const f16x8*)(H + base);
    float r[8];
#pragma unroll
    for (int j = 0; j < 8; ++j)
        r[j] = fmaxf(0.0f, fmaf((float)v[j], ssc[c0 + j], ssh[c0 + j]));
    if (OUT16) {
        f16x8 ov;
#pragma unroll
        for (int j = 0; j < 8; ++j) ov[j] = (f16)r[j];
        *(f16x8*)(o16 + base) = ov;
    } else {
        f32x4 a = {r[0], r[1], r[2], r[3]};
        f32x4 b = {r[4], r[5], r[6], r[7]};
        __builtin_nontemporal_store(a, (f32x4*)(o32 + base));
        __builtin_nontemporal_store(b, (f32x4*)(o32 + base + 4));
    }
}

extern "C" void kernel_launch(void* const* d_in, const int* in_sizes, int n_in,
                              void* d_out, int out_size, void* d_ws, size_t ws_size,
                              hipStream_t stream) {
    const float* xyz1 = (const float*)d_in[0];
    const float* xyz2 = (const float*)d_in[1];
    const float* pts1 = (const float*)d_in[2];
    const float* pts2 = (const float*)d_in[3];
    const float* w0f = (const float*)d_in[4];
    const float* g0 = (const float*)d_in[6];
    const float* be0 = (const float*)d_in[7];
    const float* w1f = (const float*)d_in[8];
    const float* g1 = (const float*)d_in[10];
    const float* be1 = (const float*)d_in[11];
    const float* w2f = (const float*)d_in[12];
    const float* g2 = (const float*)d_in[14];
    const float* be2 = (const float*)d_in[15];
    // biases b{li} cancel exactly under training-mode BN -> unused.

    char* ws = (char*)d_ws;
    // layout (bytes):
    //   x0  : [0, 50331648)              65536x384 f16; reused as bufB after layer0
    //   bufA: [50331648, +33554432)      65536x256 f16
    //         (candidate buffer ck aliases bufA: dead before layer-0 GEMM;
    //          3*16*65536*8B = 25.2MB < 33.5MB)
    //   wb  : [83886080, +393216)        all three weight matrices, f16
    //   idx : [84279296, +786432)        65536x3 i32
    //   wgt : [85065728, +786432)        65536x3 f32
    //   stat: [85852160, +6144)          3 layers x (sums[256]+sumsq[256]) f32
    f16* x0 = (f16*)(ws + 0);
    f16* bufA = (f16*)(ws + 50331648);
    f16* bufB = x0;  // alias: x0 dead after layer-0 GEMM
    f32x2* ck = (f32x2*)(ws + 50331648);
    f16* wb0 = (f16*)(ws + 83886080);
    f16* wb1 = wb0 + 98304;
    f16* wb2 = wb1 + 65536;
    int* idxb = (int*)(ws + 84279296);
    float* wgt = (float*)(ws + 85065728);
    float* stats = (float*)(ws + 85852160);
    float* sums0 = stats,        *sumsq0 = stats + 256;
    float* sums1 = stats + 512,  *sumsq1 = stats + 768;
    float* sums2 = stats + 1024, *sumsq2 = stats + 1280;

    // weights -> fp16, stats buffers -> 0 (single kernel)
    conv_f16_kernel<<<384, 256, 0, stream>>>(w0f, wb0, w1f, wb1, w2f, wb2, stats);

    // 3-NN (split-M exact scan + merge) + interpolation + concat
    nn_part_kernel<<<(BNTOT / 256) * SPLIT, 256, 0, stream>>>(xyz1, xyz2, ck);
    nn_merge_kernel<<<BNTOT / 256, 256, 0, stream>>>(ck, idxb, wgt);
    interp_kernel<<<BNTOT / 4, 256, 0, stream>>>(pts1, pts2, idxb, wgt, x0);

    // ---- layer 0: 384 -> 256 ----
    gemm_f16<384><<<dim3(512, 2), 256, 0, stream>>>(x0, wb0, bufA, sums0, sumsq0, 256);
    bnrelu_kernel<true><<<8192, 256, 0, stream>>>(bufA, sums0, sumsq0, g0, be0, bufA, nullptr, 256);

    // ---- layer 1: 256 -> 256 ----
    gemm_f16<256><<<dim3(512, 2), 256, 0, stream>>>(bufA, wb1, bufB, sums1, sumsq1, 256);
    bnrelu_kernel<true><<<8192, 256, 0, stream>>>(bufB, sums1, sumsq1, g1, be1, bufB, nullptr, 256);

    // ---- layer 2: 256 -> 128 ----
    gemm_f16<256><<<dim3(512, 1), 256, 0, stream>>>(bufB, wb2, bufA, sums2, sumsq2, 128);
    bnrelu_kernel<false><<<4096, 256, 0, stream>>>(bufA, sums2, sumsq2, g2, be2, nullptr, (float*)d_out, 128);
}